// Round 28
// baseline (246.558 us; speedup 1.0000x reference)
//
#include <hip/hip_runtime.h>
#include <hip/hip_bf16.h>
#include <math.h>

// Problem constants
#define BB 2
#define CC 128
#define HH 64
#define WW 64
#define LL 4096      // H*W
#define DI 256       // D_INNER
#define NS 16        // D_STATE
#define KK 4         // scan directions
#define OC1 42       // C // 3

// Chunked scan parameters
#define NC 256       // chunks per sequence
#define CL 16        // steps per chunk (LL/NC)

#define K3_POS 16    // positions per k3 block
#define BCW 48       // BCbuf row width: 8 dtr + 16 B + 16 C (pad to 48)

typedef __hip_bfloat16 bf16;

__device__ __forceinline__ float sigmoidf_(float x) { return 1.f / (1.f + __expf(-x)); }
__device__ __forceinline__ float siluf_(float x)    { return x * sigmoidf_(x); }

__device__ __forceinline__ int scan_pos(int k, int i) {
  if (k == 0) return i;
  if (k == 1) return ((i & 63) << 6) | (i >> 6);
  if (k == 2) return (LL - 1) - i;
  int j = (LL - 1) - i;
  return ((j & 63) << 6) | (j >> 6);
}

// ---------------------------------------------------------------------------
// K1: LN1 + in_proj (512x128), LDS-tiled GEMM. zbuf stored bf16.
// ---------------------------------------------------------------------------
__global__ __launch_bounds__(256) void k1_ln_inproj(
    const float* __restrict__ inp, const float* __restrict__ g, const float* __restrict__ b,
    const float* __restrict__ wproj, float* __restrict__ xcin, bf16* __restrict__ zbuf) {
  __shared__ float sx[64][132];   // [pos][k] LN'd input
  __shared__ float sw[128][68];   // [row_local][k_chunk]
  __shared__ float smu[64], srs[64];
  const int tid = threadIdx.x;
  const int rt = blockIdx.x & 3;
  const int pt = blockIdx.x >> 2;
  const int bb = pt >> 6;
  const int pbase = (pt & 63) << 6;

  for (int idx = tid; idx < 64 * CC; idx += 256) {
    int c = idx >> 6, pl = idx & 63;
    sx[pl][c] = inp[((size_t)bb * CC + c) * LL + pbase + pl];
  }
  __syncthreads();
  {
    int pl = tid >> 2, j = tid & 3;
    float s = 0.f, s2 = 0.f;
    for (int c = j; c < CC; c += 4) { float v = sx[pl][c]; s += v; s2 += v * v; }
    s += __shfl_xor(s, 1); s2 += __shfl_xor(s2, 1);
    s += __shfl_xor(s, 2); s2 += __shfl_xor(s2, 2);
    if (j == 0) {
      float mu = s * (1.f / CC);
      smu[pl] = mu;
      srs[pl] = rsqrtf(s2 * (1.f / CC) - mu * mu + 1e-5f);
    }
  }
  __syncthreads();
  for (int idx = tid; idx < 64 * CC; idx += 256) {
    int c = idx & 127, pl = idx >> 7;
    sx[pl][c] = (sx[pl][c] - smu[pl]) * srs[pl] * g[c] + b[c];
  }

  const int pg = tid & 7, rg = tid >> 3;
  float acc[8][4];
#pragma unroll
  for (int j = 0; j < 8; j++)
#pragma unroll
    for (int q = 0; q < 4; q++) acc[j][q] = 0.f;

  for (int kc = 0; kc < CC; kc += 64) {
    __syncthreads();
    for (int idx = tid; idx < 128 * 64; idx += 256) {
      int cl = idx & 63, rl = idx >> 6;
      sw[rl][cl] = wproj[(size_t)(rt * 128 + rl) * CC + kc + cl];
    }
    __syncthreads();
#pragma unroll 4
    for (int i = 0; i < 16; i++) {
      const int k0 = kc + 4 * i, kl0 = 4 * i;
      float4 xv[8], wv[4];
#pragma unroll
      for (int j = 0; j < 8; j++) xv[j] = *(const float4*)&sx[pg + 8 * j][k0];
#pragma unroll
      for (int q = 0; q < 4; q++) wv[q] = *(const float4*)&sw[rg + 32 * q][kl0];
#pragma unroll
      for (int j = 0; j < 8; j++)
#pragma unroll
        for (int q = 0; q < 4; q++) {
          acc[j][q] += xv[j].x * wv[q].x + xv[j].y * wv[q].y
                     + xv[j].z * wv[q].z + xv[j].w * wv[q].w;
        }
    }
  }

#pragma unroll
  for (int j = 0; j < 8; j++) {
    const int p = pbase + pg + 8 * j;
    if (rt < 2) {
      float* dst = xcin + ((size_t)bb * LL + p) * DI + rt * 128;
#pragma unroll
      for (int q = 0; q < 4; q++) dst[rg + 32 * q] = acc[j][q];
    } else {
      bf16* dst = zbuf + ((size_t)bb * LL + p) * DI + (rt - 2) * 128;
#pragma unroll
      for (int q = 0; q < 4; q++) dst[rg + 32 * q] = __float2bfloat16(acc[j][q]);
    }
  }
}

// ---------------------------------------------------------------------------
// K2: depthwise 3x3 conv + bias + silu.
// ---------------------------------------------------------------------------
__global__ __launch_bounds__(256) void k2_dwconv(
    const float* __restrict__ xcin, const float* __restrict__ cw, const float* __restrict__ cb,
    float* __restrict__ xconv) {
  const int w0 = (blockIdx.x & 7) * 8;
  const int hh = (blockIdx.x >> 3) & 63;
  const int bb = blockIdx.x >> 9;
  const int d = threadIdx.x;

  float wv[9];
#pragma unroll
  for (int kk = 0; kk < 9; kk++) wv[kk] = cw[d * 9 + kk];
  const float bias = cb[d];

  float xin[3][10];
#pragma unroll
  for (int kh = 0; kh < 3; kh++) {
    int r = hh + kh - 1;
    bool vr = (r >= 0 && r < HH);
#pragma unroll
    for (int c = 0; c < 10; c++) {
      int cc2 = w0 + c - 1;
      bool vc = (cc2 >= 0 && cc2 < WW);
      xin[kh][c] = (vr && vc) ? xcin[((size_t)bb * LL + r * WW + cc2) * DI + d] : 0.f;
    }
  }
#pragma unroll
  for (int j = 0; j < 8; j++) {
    float acc = bias;
#pragma unroll
    for (int kh = 0; kh < 3; kh++)
#pragma unroll
      for (int kw = 0; kw < 3; kw++)
        acc += wv[kh * 3 + kw] * xin[kh][j + kw];
    xconv[((size_t)bb * LL + hh * WW + w0 + j) * DI + d] = siluf_(acc);
  }
}

// ---------------------------------------------------------------------------
// K3: x_proj GEMM (160x256) -> BCbuf48, LDS-tiled both operands. (R15 form)
// ---------------------------------------------------------------------------
__global__ __launch_bounds__(256) void k3_proj(
    const float* __restrict__ xconv, const float* __restrict__ xpw,
    float* __restrict__ BCbuf) {
  __shared__ float sx[16][68];    // k-chunk of xconv
  __shared__ float sw[160][68];   // k-chunk of x_proj_w
  const int tid = threadIdx.x;
  const int bb = blockIdx.x >> 8;
  const int pbase = (blockIdx.x & 255) << 4;  // 16 positions

  const int pg = tid & 7, rb = tid >> 3;
  float acc[2][5];
#pragma unroll
  for (int j = 0; j < 2; j++)
#pragma unroll
    for (int q = 0; q < 5; q++) acc[j][q] = 0.f;

  for (int kc = 0; kc < DI; kc += 64) {
    __syncthreads();
    for (int idx = tid; idx < 16 * 64; idx += 256) {
      int cl = idx & 63, pl = idx >> 6;
      sx[pl][cl] = xconv[((size_t)bb * LL + pbase + pl) * DI + kc + cl];
    }
    for (int idx = tid; idx < 160 * 64; idx += 256) {
      int cl = idx & 63, rl = idx >> 6;
      sw[rl][cl] = xpw[(size_t)rl * DI + kc + cl];
    }
    __syncthreads();
#pragma unroll 4
    for (int i = 0; i < 16; i++) {
      float4 xv[2], wv[5];
#pragma unroll
      for (int j = 0; j < 2; j++) xv[j] = *(const float4*)&sx[2 * pg + j][4 * i];
#pragma unroll
      for (int q = 0; q < 5; q++) wv[q] = *(const float4*)&sw[rb + 32 * q][4 * i];
#pragma unroll
      for (int j = 0; j < 2; j++)
#pragma unroll
        for (int q = 0; q < 5; q++) {
          acc[j][q] += xv[j].x * wv[q].x + xv[j].y * wv[q].y
                     + xv[j].z * wv[q].z + xv[j].w * wv[q].w;
        }
    }
  }

#pragma unroll
  for (int j = 0; j < 2; j++) {
    const int p = pbase + 2 * pg + j;
#pragma unroll
    for (int q = 0; q < 5; q++) {
      const int r = rb + 32 * q;
      const int k = r / 40, c0 = r - k * 40;
      BCbuf[((size_t)(bb * KK + k) * LL + p) * BCW + c0] = acc[j][q];
    }
  }
}

// ---------------------------------------------------------------------------
// K4a: chunked scan phase 1 with inline dt. Stores sumdt (fp32) + Bc (bf16).
// ---------------------------------------------------------------------------
__global__ __launch_bounds__(256) void k4a_chunk(
    const float* __restrict__ xconv, const float* __restrict__ BCbuf,
    const float* __restrict__ A_logs, const float* __restrict__ dtw,
    const float* __restrict__ dtb,
    float* __restrict__ csS, bf16* __restrict__ csB) {
  __shared__ float sBC[CL][26];
  const int d = threadIdx.x;
  const int chunk = blockIdx.x & (NC - 1);
  const int t = blockIdx.x / NC;
  const int k = t & 3;
  const int bb = t >> 2;
  const int bk = bb * KK + k;
  const int base = chunk * CL;

  for (int idx = d; idx < CL * 24; idx += 256) {
    int ii = idx / 24, j = idx - ii * 24;
    int pos = scan_pos(k, base + ii);
    sBC[ii][j] = BCbuf[((size_t)bk * LL + pos) * BCW + j];
  }
  float a[NS];
  bool fast = true;
#pragma unroll
  for (int n = 0; n < NS; n++) {
    a[n] = -__expf(A_logs[((size_t)k * DI + d) * NS + n]);
    fast = fast && (fabsf(a[n] + (float)(n + 1)) < 1e-3f * (n + 1));
  }
  const float* wdt = dtw + ((size_t)k * DI + d) * 8;
  const float4 wd0 = *(const float4*)wdt;
  const float4 wd1 = *(const float4*)(wdt + 4);
  const float bdt = dtb[k * DI + d];
  __syncthreads();

  const float* x_p = xconv + (size_t)bb * LL * DI + d;

  float Bc[NS];
#pragma unroll
  for (int n = 0; n < NS; n++) Bc[n] = 0.f;
  float sumdt = 0.f;

  if (fast) {
#pragma unroll
    for (int half = 0; half < CL / 8; half++) {
      float xvr[8];
#pragma unroll
      for (int j = 0; j < 8; j++)
        xvr[j] = x_p[(size_t)scan_pos(k, base + half * 8 + j) * DI];
#pragma unroll
      for (int j = 0; j < 8; j++) {
        const int ii = half * 8 + j;
        const float* dr = sBC[ii];
        float u = bdt + wd0.x * dr[0] + wd0.y * dr[1] + wd0.z * dr[2] + wd0.w * dr[3]
                      + wd1.x * dr[4] + wd1.y * dr[5] + wd1.z * dr[6] + wd1.w * dr[7];
        float t2 = __expf(u);
        float E = __builtin_amdgcn_rcpf(1.f + t2);   // = exp(-dt)
        float dt = u > 20.f ? u : -0.69314718056f * __log2f(E);
        sumdt += dt;
        float dtx = dt * xvr[j];
        float E2 = E * E;
        float dA1 = E, dA2 = E2;
#pragma unroll
        for (int n = 0; n < NS; n += 2) {
          Bc[n] = dA1 * Bc[n] + dtx * sBC[ii][8 + n];
          Bc[n + 1] = dA2 * Bc[n + 1] + dtx * sBC[ii][9 + n];
          dA1 *= E2; dA2 *= E2;
        }
      }
    }
  } else {
#pragma unroll 2
    for (int ii = 0; ii < CL; ii++) {
      int pos = scan_pos(k, base + ii);
      float xv = x_p[(size_t)pos * DI];
      const float* dr = sBC[ii];
      float u = bdt + wd0.x * dr[0] + wd0.y * dr[1] + wd0.z * dr[2] + wd0.w * dr[3]
                    + wd1.x * dr[4] + wd1.y * dr[5] + wd1.z * dr[6] + wd1.w * dr[7];
      float t2 = __expf(u);
      float dt = u > 20.f ? u : log1pf(t2);
      sumdt += dt;
      float dtx = dt * xv;
#pragma unroll
      for (int n = 0; n < NS; n++) {
        float dA = __expf(dt * a[n]);
        Bc[n] = dA * Bc[n] + dtx * sBC[ii][8 + n];
      }
    }
  }
  csS[((size_t)bk * NC + chunk) * DI + d] = sumdt;
  size_t e = ((size_t)(bk * NC + chunk) * NS) * DI + d;
#pragma unroll
  for (int n = 0; n < NS; n++)
    csB[e + (size_t)n * DI] = __float2bfloat16(Bc[n]);
}

// ---------------------------------------------------------------------------
// K4b: scan NC chunk summaries -> h_in (bf16). Ap[n] = exp(a_n * sumdt).
// d-split x2: grid = BB*KK*NS*2 = 256 blocks x 128 threads (all CUs busy).
// ---------------------------------------------------------------------------
__global__ __launch_bounds__(128) void k4b_scanchunks(
    const float* __restrict__ csS, const bf16* __restrict__ csB,
    const float* __restrict__ A_logs, bf16* __restrict__ hin) {
  const int d = threadIdx.x + ((blockIdx.x & 1) << 7);
  const int n = (blockIdx.x >> 1) & (NS - 1);
  const int bk = blockIdx.x >> 5;
  const int k = bk & 3;
  const float an = -__expf(A_logs[((size_t)k * DI + d) * NS + n]);
  const size_t strideB = (size_t)NS * DI;
  size_t e = ((size_t)bk * NC * NS + n) * DI + d;
  float H = 0.f;
  for (int c0 = 0; c0 < NC; c0 += 16) {
    float Ea[16], Bv[16];
#pragma unroll
    for (int j = 0; j < 16; j++) {
      Ea[j] = an * csS[((size_t)bk * NC + c0 + j) * DI + d];
      Bv[j] = __bfloat162float(csB[e + (size_t)j * strideB]);
    }
#pragma unroll
    for (int j = 0; j < 16; j++) Ea[j] = __expf(Ea[j]);
#pragma unroll
    for (int j = 0; j < 16; j++) {
      hin[e + (size_t)j * strideB] = __float2bfloat16(H);
      H = Ea[j] * H + Bv[j];
    }
    e += (size_t)16 * strideB;
  }
}

// ---------------------------------------------------------------------------
// K4c: chunked scan phase 3 — recurrence from h_in (bf16), emit y (bf16).
// ---------------------------------------------------------------------------
__global__ __launch_bounds__(256) void k4c_scan(
    const float* __restrict__ xconv, const float* __restrict__ BCbuf,
    const float* __restrict__ A_logs, const float* __restrict__ dtw,
    const float* __restrict__ dtb, const float* __restrict__ Ds,
    const bf16* __restrict__ hin, bf16* __restrict__ ys) {
  __shared__ float sBC[CL][BCW];
  const int d = threadIdx.x;
  const int chunk = blockIdx.x & (NC - 1);
  const int t = blockIdx.x / NC;
  const int k = t & 3;
  const int bb = t >> 2;
  const int bk = bb * KK + k;
  const int base = chunk * CL;

  for (int idx = d; idx < CL * 40; idx += 256) {
    int ii = idx / 40, j = idx - ii * 40;
    int pos = scan_pos(k, base + ii);
    sBC[ii][j] = BCbuf[((size_t)bk * LL + pos) * BCW + j];
  }
  float a[NS], h[NS];
  bool fast = true;
  const size_t eh = ((size_t)(bk * NC + chunk) * NS) * DI + d;
#pragma unroll
  for (int n = 0; n < NS; n++) {
    a[n] = -__expf(A_logs[((size_t)k * DI + d) * NS + n]);
    fast = fast && (fabsf(a[n] + (float)(n + 1)) < 1e-3f * (n + 1));
    h[n] = __bfloat162float(hin[eh + (size_t)n * DI]);
  }
  const float* wdt = dtw + ((size_t)k * DI + d) * 8;
  const float4 wd0 = *(const float4*)wdt;
  const float4 wd1 = *(const float4*)(wdt + 4);
  const float bdt = dtb[k * DI + d];
  const float Dd = Ds[k * DI + d];
  __syncthreads();

  const float* x_p = xconv + (size_t)bb * LL * DI + d;
  bf16* ys_p = ys + (size_t)bk * LL * DI + d;

  if (fast) {
#pragma unroll
    for (int half = 0; half < CL / 8; half++) {
      float xvr[8];
#pragma unroll
      for (int j = 0; j < 8; j++)
        xvr[j] = x_p[(size_t)scan_pos(k, base + half * 8 + j) * DI];
#pragma unroll
      for (int j = 0; j < 8; j++) {
        const int ii = half * 8 + j;
        const float* dr = sBC[ii];
        float u = bdt + wd0.x * dr[0] + wd0.y * dr[1] + wd0.z * dr[2] + wd0.w * dr[3]
                      + wd1.x * dr[4] + wd1.y * dr[5] + wd1.z * dr[6] + wd1.w * dr[7];
        float t2 = __expf(u);
        float E = __builtin_amdgcn_rcpf(1.f + t2);   // = exp(-dt)
        float dt = u > 20.f ? u : -0.69314718056f * __log2f(E);
        float dtx = dt * xvr[j];
        float y = xvr[j] * Dd;
        float E2 = E * E;
        float dA1 = E, dA2 = E2;
#pragma unroll
        for (int n = 0; n < NS; n += 2) {
          h[n] = dA1 * h[n] + dtx * sBC[ii][8 + n];
          y += h[n] * sBC[ii][24 + n];
          h[n + 1] = dA2 * h[n + 1] + dtx * sBC[ii][9 + n];
          y += h[n + 1] * sBC[ii][25 + n];
          dA1 *= E2; dA2 *= E2;
        }
        ys_p[(size_t)scan_pos(k, base + ii) * DI] = __float2bfloat16(y);
      }
    }
  } else {
#pragma unroll 2
    for (int ii = 0; ii < CL; ii++) {
      int pos = scan_pos(k, base + ii);
      float xv = x_p[(size_t)pos * DI];
      const float* dr = sBC[ii];
      float u = bdt + wd0.x * dr[0] + wd0.y * dr[1] + wd0.z * dr[2] + wd0.w * dr[3]
                    + wd1.x * dr[4] + wd1.y * dr[5] + wd1.z * dr[6] + wd1.w * dr[7];
      float t2 = __expf(u);
      float dt = u > 20.f ? u : log1pf(t2);
      float dtx = dt * xv;
      float y = xv * Dd;
#pragma unroll
      for (int n = 0; n < NS; n++) {
        float dA = __expf(dt * a[n]);
        h[n] = dA * h[n] + dtx * sBC[ii][8 + n];
        y += h[n] * sBC[ii][24 + n];
      }
      ys_p[(size_t)pos * DI] = __float2bfloat16(y);
    }
  }
}

// ---------------------------------------------------------------------------
// K5: FUSED. 4-dir sum (bf16 ys) + out_norm LN + silu(bf16 z) into LDS, then
// out_proj GEMM + skip -> xresT (NCHW); LN2 -> ln2.
// opw k-chunk = 32 -> sw[128][36] (18.4KB); total LDS ~43.6KB -> 3 blocks/CU.
// ---------------------------------------------------------------------------
__global__ __launch_bounds__(256) void k5_fused(
    const bf16* __restrict__ ys, const bf16* __restrict__ zbuf,
    const float* __restrict__ ong, const float* __restrict__ onb,
    const float* __restrict__ opw,
    const float* __restrict__ inp, const float* __restrict__ sk,
    const float* __restrict__ g2, const float* __restrict__ b2,
    float* __restrict__ xresT, float* __restrict__ ln2) {
  __shared__ float sy[16][260];   // activated input (full K)
  __shared__ float sw[128][36];   // k-chunk (32) of opw
  __shared__ float sr[16][132];
  __shared__ float smu[16], srs[16];
  const int tid = threadIdx.x;
  const int bb = blockIdx.x >> 8;
  const int pbase = (blockIdx.x & 255) << 4;  // 16 positions

  for (int idx = tid; idx < 16 * DI; idx += 256) {
    int d = idx & 255, pl = idx >> 8;
    size_t o0 = (((size_t)bb * KK + 0) * LL + pbase + pl) * DI + d;
    const size_t st = (size_t)LL * DI;
    sy[pl][d] = __bfloat162float(ys[o0]) + __bfloat162float(ys[o0 + st])
              + __bfloat162float(ys[o0 + 2 * st]) + __bfloat162float(ys[o0 + 3 * st]);
  }
  __syncthreads();
  {
    int pl = tid >> 4, j = tid & 15;
    float s = 0.f, s2 = 0.f;
    for (int d = j; d < DI; d += 16) { float v = sy[pl][d]; s += v; s2 += v * v; }
#pragma unroll
    for (int m = 1; m < 16; m <<= 1) { s += __shfl_xor(s, m); s2 += __shfl_xor(s2, m); }
    if (j == 0) {
      float mu = s * (1.f / DI);
      smu[pl] = mu;
      srs[pl] = rsqrtf(s2 * (1.f / DI) - mu * mu + 1e-5f);
    }
  }
  __syncthreads();
  for (int idx = tid; idx < 16 * DI; idx += 256) {
    int d = idx & 255, pl = idx >> 8;
    float zv = __bfloat162float(zbuf[((size_t)bb * LL + pbase + pl) * DI + d]);
    sy[pl][d] = ((sy[pl][d] - smu[pl]) * srs[pl] * ong[d] + onb[d]) * siluf_(zv);
  }

  const int pg = tid & 7, rb = tid >> 3;      // pos-pair group, c-base
  float acc[2][4];
#pragma unroll
  for (int j = 0; j < 2; j++)
#pragma unroll
    for (int q = 0; q < 4; q++) acc[j][q] = 0.f;

  for (int kc = 0; kc < DI; kc += 32) {
    __syncthreads();
    for (int idx = tid; idx < 128 * 32; idx += 256) {
      int cl = idx & 31, rl = idx >> 5;
      sw[rl][cl] = opw[(size_t)rl * DI + kc + cl];
    }
    __syncthreads();
#pragma unroll 4
    for (int i = 0; i < 8; i++) {
      float4 xv[2], wv[4];
#pragma unroll
      for (int j = 0; j < 2; j++) xv[j] = *(const float4*)&sy[2 * pg + j][kc + 4 * i];
#pragma unroll
      for (int q = 0; q < 4; q++) wv[q] = *(const float4*)&sw[rb + 32 * q][4 * i];
#pragma unroll
      for (int j = 0; j < 2; j++)
#pragma unroll
        for (int q = 0; q < 4; q++) {
          acc[j][q] += xv[j].x * wv[q].x + xv[j].y * wv[q].y
                     + xv[j].z * wv[q].z + xv[j].w * wv[q].w;
        }
    }
  }

#pragma unroll
  for (int j = 0; j < 2; j++) {
    const int p = pbase + 2 * pg + j;
#pragma unroll
    for (int q = 0; q < 4; q++) {
      const int c = rb + 32 * q;
      float r = inp[((size_t)bb * CC + c) * LL + p] * sk[c] + acc[j][q];
      sr[2 * pg + j][c] = r;
    }
  }
  __syncthreads();
  {
    int pl = tid >> 4, jj = tid & 15;
    float s = 0.f, s2 = 0.f;
    for (int c = jj; c < CC; c += 16) { float v = sr[pl][c]; s += v; s2 += v * v; }
#pragma unroll
    for (int m = 1; m < 16; m <<= 1) { s += __shfl_xor(s, m); s2 += __shfl_xor(s2, m); }
    if (jj == 0) {
      float mu = s * (1.f / CC);
      smu[pl] = mu;
      srs[pl] = rsqrtf(s2 * (1.f / CC) - mu * mu + 1e-5f);
    }
  }
  __syncthreads();
  for (int idx = tid; idx < 16 * CC; idx += 256) {
    int pl = idx & 15, c = idx >> 4;
    float r = sr[pl][c];
    size_t o = ((size_t)bb * CC + c) * LL + pbase + pl;
    xresT[o] = r;
    ln2[o] = (r - smu[pl]) * srs[pl] * g2[c] + b2[c];
  }
}

// ---------------------------------------------------------------------------
// K6a: CAB conv1 partials. ic K-split 16 chunks of 8 (was 8x16): grid 512,
// LDS ~25KB, per-block i-loop 8. Same FMA:load ratio, 2x block parallelism.
// ---------------------------------------------------------------------------
__global__ __launch_bounds__(256) void k6a_conv1(
    const float* __restrict__ ln2, const float* __restrict__ w1,
    float* __restrict__ pc1) {
  __shared__ float sIn[8][6][68];
  __shared__ float sw[8 * 9 * OC1];
  const int tid = threadIdx.x;
  const int icq = blockIdx.x & 15;
  const int h4  = (blockIdx.x >> 4) & 15;
  const int bb  = blockIdx.x >> 8;
  const int icb = icq * 8;

  for (int idx = tid; idx < 8 * 6 * 66; idx += 256) {
    int i = idx / 396, rem = idx % 396;
    int rr = rem / 66, j = rem % 66;
    int r = h4 * 4 + rr - 1, c2 = j - 1;
    float v = 0.f;
    if (r >= 0 && r < HH && c2 >= 0 && c2 < WW)
      v = ln2[((size_t)bb * CC + icb + i) * LL + r * WW + c2];
    sIn[i][rr][j] = v;
  }
  for (int idx = tid; idx < OC1 * 8 * 9; idx += 256) {
    int oc = idx / 72, rem = idx % 72;
    int i = rem / 9, kk = rem % 9;
    sw[(i * 9 + kk) * OC1 + oc] = w1[((size_t)oc * CC + icb + i) * 9 + kk];
  }
  __syncthreads();

  const int wq = tid & 7, hq = (tid >> 3) & 3, ocg = tid >> 5;
  float acc[6][8];
#pragma unroll
  for (int q = 0; q < 6; q++)
#pragma unroll
    for (int ww = 0; ww < 8; ww++) acc[q][ww] = 0.f;

  for (int i = 0; i < 8; i++) {
    float xin[3][10];
#pragma unroll
    for (int kh = 0; kh < 3; kh++)
#pragma unroll
      for (int j = 0; j < 10; j++) xin[kh][j] = sIn[i][hq + kh][wq * 8 + j];
#pragma unroll
    for (int q = 0; q < 6; q++) {
      int oc = ocg + 8 * q;
      if (oc >= OC1) break;
      float wv[9];
#pragma unroll
      for (int kk = 0; kk < 9; kk++) wv[kk] = sw[(i * 9 + kk) * OC1 + oc];
#pragma unroll
      for (int kh = 0; kh < 3; kh++)
#pragma unroll
        for (int kw = 0; kw < 3; kw++)
#pragma unroll
          for (int ww = 0; ww < 8; ww++)
            acc[q][ww] += wv[kh * 3 + kw] * xin[kh][ww + kw];
    }
  }

  const int hrow = h4 * 4 + hq;
#pragma unroll
  for (int q = 0; q < 6; q++) {
    int oc = ocg + 8 * q;
    if (oc >= OC1) break;
    float* dst = pc1 + (((size_t)icq * BB + bb) * OC1 + oc) * LL + hrow * WW + wq * 8;
    *(float4*)dst       = make_float4(acc[q][0], acc[q][1], acc[q][2], acc[q][3]);
    *(float4*)(dst + 4) = make_float4(acc[q][4], acc[q][5], acc[q][6], acc[q][7]);
  }
}

// ---------------------------------------------------------------------------
// K6b: reduce 16 partials + bias + exact GELU -> t1. L-split x4:
// grid = BB*42*4 = 336 blocks, exactly 1 float4-iteration per thread.
// ---------------------------------------------------------------------------
__global__ __launch_bounds__(256) void k6b_reduce(
    const float* __restrict__ pc1, const float* __restrict__ b1,
    float* __restrict__ t1) {
  const int seg = blockIdx.x & 3;
  const int t = blockIdx.x >> 2;
  const int oc = t % OC1;
  const int bb = t / OC1;
  const float bias = b1[oc];
  const size_t st = (size_t)BB * OC1 * LL;
  const float* src = pc1 + ((size_t)bb * OC1 + oc) * LL;
  float* dst = t1 + ((size_t)bb * OC1 + oc) * LL;
  const int i0 = seg * (LL / 16), i1 = i0 + LL / 16;   // float4 index range
  for (int i = i0 + (int)threadIdx.x; i < i1; i += 256) {
    float4 s = ((const float4*)src)[i];
#pragma unroll
    for (int icq = 1; icq < 16; icq++) {
      float4 v = *(const float4*)(src + (size_t)icq * st + i * 4);
      s.x += v.x; s.y += v.y; s.z += v.z; s.w += v.w;
    }
    float r[4] = {s.x + bias, s.y + bias, s.z + bias, s.w + bias};
#pragma unroll
    for (int q = 0; q < 4; q++)
      r[q] = 0.5f * r[q] * (1.f + erff(r[q] * 0.70710678118654752f));
    ((float4*)dst)[i] = make_float4(r[0], r[1], r[2], r[3]);
  }
}

// ---------------------------------------------------------------------------
// K7: CAB conv2 partials. ic K-split x2 (chunks of 21); transposed weight
// tile swT[32][196] (conflict-free staging + reads). (R17 proven form)
// ---------------------------------------------------------------------------
__global__ __launch_bounds__(256) void k7_conv2(
    const float* __restrict__ t1, const float* __restrict__ w2,
    float* __restrict__ pc2) {
  __shared__ float sIn[21][4][68];
  __shared__ float swT[32 * 196];   // [oc_local][i*9+kk], row pad 196
  const int tid = threadIdx.x;
  const int icq = blockIdx.x & 1;
  const int h2  = (blockIdx.x >> 1) & 31;
  const int ocq = (blockIdx.x >> 6) & 3;
  const int bb  = blockIdx.x >> 8;
  const int icb = icq * 21;

  for (int idx = tid; idx < 21 * 4 * 66; idx += 256) {
    int i = idx / 264, rem = idx % 264;
    int rr = rem / 66, j = rem % 66;
    int r = h2 * 2 + rr - 1, c2 = j - 1;
    float v = 0.f;
    if (r >= 0 && r < HH && c2 >= 0 && c2 < WW)
      v = t1[((size_t)bb * OC1 + icb + i) * LL + r * WW + c2];
    sIn[i][rr][j] = v;
  }
  for (int idx = tid; idx < 32 * 189; idx += 256) {
    int ol = idx / 189, ikk = idx % 189;
    swT[ol * 196 + ikk] = w2[(size_t)(ocq * 32 + ol) * (OC1 * 9) + icb * 9 + ikk];
  }
  __syncthreads();

  const int wq = tid & 7, hq = (tid >> 3) & 1, ocg = tid >> 4;
  float acc[2][8];
#pragma unroll
  for (int q = 0; q < 2; q++)
#pragma unroll
    for (int ww = 0; ww < 8; ww++) acc[q][ww] = 0.f;

  for (int i = 0; i < 21; i++) {
    float xin[3][10];
#pragma unroll
    for (int kh = 0; kh < 3; kh++)
#pragma unroll
      for (int j = 0; j < 10; j++) xin[kh][j] = sIn[i][hq + kh][wq * 8 + j];
#pragma unroll
    for (int q = 0; q < 2; q++) {
      int ol = ocg + 16 * q;
      float wv[9];
#pragma unroll
      for (int kk = 0; kk < 9; kk++) wv[kk] = swT[ol * 196 + i * 9 + kk];
#pragma unroll
      for (int kh = 0; kh < 3; kh++)
#pragma unroll
        for (int kw = 0; kw < 3; kw++)
#pragma unroll
          for (int ww = 0; ww < 8; ww++)
            acc[q][ww] += wv[kh * 3 + kw] * xin[kh][ww + kw];
    }
  }

  const int hrow = h2 * 2 + hq;
#pragma unroll
  for (int q = 0; q < 2; q++) {
    int oc = ocq * 32 + ocg + 16 * q;
    float* dst = pc2 + (((size_t)icq * BB + bb) * CC + oc) * LL + hrow * WW + wq * 8;
    *(float4*)dst       = make_float4(acc[q][0], acc[q][1], acc[q][2], acc[q][3]);
    *(float4*)(dst + 4) = make_float4(acc[q][4], acc[q][5], acc[q][6], acc[q][7]);
  }
}

// ---------------------------------------------------------------------------
// K8: reduce 2 conv2 partials + bias -> t2; partial sums of mean. L-split x2:
// grid = BB*CC*2 = 512 blocks; smean_p[half][bc] holds half-mean (pre-scaled).
// ---------------------------------------------------------------------------
__global__ __launch_bounds__(256) void k8_mean(
    const float* __restrict__ pc2, const float* __restrict__ b2,
    float* __restrict__ t2, float* __restrict__ smean_p) {
  __shared__ float red[4];
  const int half = blockIdx.x & 1;
  const int bc = blockIdx.x >> 1;
  const int bb = bc >> 7, c = bc & 127;
  const float bias = b2[c];
  const size_t st = (size_t)BB * CC * LL;
  const float* src = pc2 + ((size_t)bb * CC + c) * LL;
  float* dst = t2 + (size_t)bc * LL;
  float s = 0.f;
  const int i0 = half * (LL / 8), i1 = i0 + LL / 8;    // float4 index range
  for (int i = i0 + (int)threadIdx.x; i < i1; i += 256) {
    float4 v0 = ((const float4*)src)[i];
    float4 v1 = *(const float4*)(src + st + i * 4);
    float4 r = make_float4(v0.x + v1.x + bias, v0.y + v1.y + bias,
                           v0.z + v1.z + bias, v0.w + v1.w + bias);
    ((float4*)dst)[i] = r;
    s += r.x + r.y + r.z + r.w;
  }
#pragma unroll
  for (int m = 1; m < 64; m <<= 1) s += __shfl_xor(s, m);
  if ((threadIdx.x & 63) == 0) red[threadIdx.x >> 6] = s;
  __syncthreads();
  if (threadIdx.x == 0)
    smean_p[half * (BB * CC) + bc] = (red[0] + red[1] + red[2] + red[3]) * (1.f / LL);
}

// ---------------------------------------------------------------------------
// K10: CA MLP (recomputed per block from 2 smean partials) + final combine.
// L-split x2: grid = BB*CC*2 = 512 blocks.
// ---------------------------------------------------------------------------
__global__ __launch_bounds__(256) void k10_final(
    const float* __restrict__ xresT, const float* __restrict__ t2,
    const float* __restrict__ smean_p,
    const float* __restrict__ cw1, const float* __restrict__ cb1,
    const float* __restrict__ cw2, const float* __restrict__ cb2,
    const float* __restrict__ sk2, float* __restrict__ out) {
  __shared__ float mid[4];
  const int tid = threadIdx.x;
  const int phalf = blockIdx.x & 1;
  const int bc = blockIdx.x >> 1;
  const int bb = bc >> 7, c = bc & 127;

  {
    const int wv = tid >> 6, ln = tid & 63;
    const float* sp0 = smean_p;
    const float* sp1 = smean_p + BB * CC;
    float m0 = sp0[bb * CC + ln] + sp1[bb * CC + ln];
    float m1 = sp0[bb * CC + 64 + ln] + sp1[bb * CC + 64 + ln];
    float s = cw1[wv * CC + ln] * m0 + cw1[wv * CC + 64 + ln] * m1;
#pragma unroll
    for (int m = 1; m < 64; m <<= 1) s += __shfl_xor(s, m);
    if (ln == 0) mid[wv] = fmaxf(s + cb1[wv], 0.f);
  }
  __syncthreads();
  float a = cb2[c];
#pragma unroll
  for (int m = 0; m < 4; m++) a += cw2[c * 4 + m] * mid[m];
  const float sv = sigmoidf_(a);

  const float ss = sk2[c];
  const float* t2r = t2 + (size_t)bc * LL;
  const float* xrt = xresT + (size_t)bc * LL;
  float* outr = out + (size_t)bc * LL;
  const int e0 = phalf * (LL / 2), e1 = e0 + LL / 2;
  for (int i = e0 + tid; i < e1; i += 256)
    outr[i] = xrt[i] * ss + t2r[i] * sv;
}

// ---------------------------------------------------------------------------

extern "C" void kernel_launch(void* const* d_in, const int* in_sizes, int n_in,
                              void* d_out, int out_size, void* d_ws, size_t ws_size,
                              hipStream_t stream) {
  const float* input      = (const float*)d_in[0];
  const float* ln1_g      = (const float*)d_in[1];
  const float* ln1_b      = (const float*)d_in[2];
  const float* skip_scale = (const float*)d_in[3];
  const float* skip_scale2= (const float*)d_in[4];
  const float* ln2_g      = (const float*)d_in[5];
  const float* ln2_b      = (const float*)d_in[6];
  const float* in_proj_w  = (const float*)d_in[7];
  const float* conv_w     = (const float*)d_in[8];
  const float* conv_b     = (const float*)d_in[9];
  const float* x_proj_w   = (const float*)d_in[10];
  const float* dt_w       = (const float*)d_in[11];
  const float* dt_b       = (const float*)d_in[12];
  const float* A_logs     = (const float*)d_in[13];
  const float* Ds         = (const float*)d_in[14];
  const float* out_norm_g = (const float*)d_in[15];
  const float* out_norm_b = (const float*)d_in[16];
  const float* out_proj_w = (const float*)d_in[17];
  const float* cab_w1     = (const float*)d_in[18];
  const float* cab_b1     = (const float*)d_in[19];
  const float* cab_w2     = (const float*)d_in[20];
  const float* cab_b2     = (const float*)d_in[21];
  const float* ca_w1      = (const float*)d_in[22];
  const float* ca_b1      = (const float*)d_in[23];
  const float* ca_w2      = (const float*)d_in[24];
  const float* ca_b2      = (const float*)d_in[25];

  float* ws = (float*)d_ws;
  float* xcin  = ws;                                   // B*L*256 f32
  float* zb_f  = xcin + (size_t)BB * LL * DI;          // B*L*256 region (bf16 used)
  bf16*  zbuf  = (bf16*)zb_f;
  float* xconv = zb_f + (size_t)BB * LL * DI;          // B*L*256 f32
  float* BCbuf = xconv + (size_t)BB * LL * DI;         // B*4*L*48 f32
  float* ysb_f = BCbuf + (size_t)BB * KK * LL * BCW;   // B*4*L*256 region (8.39M f32)
  float* xresT = ysb_f + (size_t)BB * KK * LL * DI;    // B*128*L (NCHW) f32
  float* ln2b  = xresT + (size_t)BB * LL * CC;         // B*128*L f32
  float* t1b   = ln2b + (size_t)BB * CC * LL;          // B*42*L f32
  float* t2b   = t1b + (size_t)BB * OC1 * LL;          // B*128*L f32
  float* smean = t2b + (size_t)BB * CC * LL;           // 2 x B*128 (partials)
  float* hin_f = smean + 2 * BB * CC;                  // B*K*NC*NS*DI region (8.39M f32)
  bf16*  hinbuf= (bf16*)hin_f;
  float* csS   = hin_f + (size_t)BB * KK * NC * NS * DI;  // B*K*NC*DI f32 (sumdt)
  // Aliases (disjoint lifetimes):
  //  csB (bf16) in ysb: k4a->k4b. ys (bf16) in ysb: k4c->k5.
  //  pc1 (16 partials, 5.51M f32) in ysb after k5 (<= 8.39M region).
  //  pc2 (4.19M f32) in hin region after k5 (hin dead after k4c; <= 8.39M).
  bf16*  csB   = (bf16*)ysb_f;
  bf16*  ysbuf = (bf16*)ysb_f;
  float* pc1   = ysb_f;
  float* pc2   = hin_f;

  k1_ln_inproj<<<512, 256, 0, stream>>>(input, ln1_g, ln1_b, in_proj_w, xcin, zbuf);
  k2_dwconv<<<BB * HH * (WW / 8), 256, 0, stream>>>(xcin, conv_w, conv_b, xconv);
  k3_proj<<<BB * (LL / K3_POS), 256, 0, stream>>>(xconv, x_proj_w, BCbuf);
  k4a_chunk<<<BB * KK * NC, 256, 0, stream>>>(xconv, BCbuf, A_logs, dt_w, dt_b, csS, csB);
  k4b_scanchunks<<<BB * KK * NS * 2, 128, 0, stream>>>(csS, csB, A_logs, hinbuf);
  k4c_scan<<<BB * KK * NC, 256, 0, stream>>>(xconv, BCbuf, A_logs, dt_w, dt_b, Ds, hinbuf, ysbuf);
  k5_fused<<<BB * (LL / 16), 256, 0, stream>>>(ysbuf, zbuf, out_norm_g, out_norm_b, out_proj_w,
                                               input, skip_scale, ln2_g, ln2_b, xresT, ln2b);
  k6a_conv1<<<BB * 16 * 16, 256, 0, stream>>>(ln2b, cab_w1, pc1);
  k6b_reduce<<<BB * OC1 * 4, 256, 0, stream>>>(pc1, cab_b1, t1b);
  k7_conv2<<<BB * 4 * 32 * 2, 256, 0, stream>>>(t1b, cab_w2, pc2);
  k8_mean<<<BB * CC * 2, 256, 0, stream>>>(pc2, cab_b2, t2b, smean);
  k10_final<<<BB * CC * 2, 256, 0, stream>>>(xresT, t2b, smean, ca_w1, ca_b1, ca_w2, ca_b2,
                                             skip_scale2, (float*)d_out);
}

// Round 29
// 235.296 us; speedup vs baseline: 1.0479x; 1.0479x over previous
//
#include <hip/hip_runtime.h>
#include <hip/hip_bf16.h>
#include <math.h>

// Problem constants
#define BB 2
#define CC 128
#define HH 64
#define WW 64
#define LL 4096      // H*W
#define DI 256       // D_INNER
#define NS 16        // D_STATE
#define KK 4         // scan directions
#define OC1 42       // C // 3

// Chunked scan parameters
#define NC 256       // chunks per sequence
#define CL 16        // steps per chunk (LL/NC)

#define K3_POS 16    // positions per k3 block
#define BCW 48       // BCbuf row width: 8 dtr + 16 B + 16 C (pad to 48)

typedef __hip_bfloat16 bf16;

__device__ __forceinline__ float sigmoidf_(float x) { return 1.f / (1.f + __expf(-x)); }
__device__ __forceinline__ float siluf_(float x)    { return x * sigmoidf_(x); }

__device__ __forceinline__ int scan_pos(int k, int i) {
  if (k == 0) return i;
  if (k == 1) return ((i & 63) << 6) | (i >> 6);
  if (k == 2) return (LL - 1) - i;
  int j = (LL - 1) - i;
  return ((j & 63) << 6) | (j >> 6);
}

// ---------------------------------------------------------------------------
// K1: LN1 + in_proj (512x128), LDS-tiled GEMM. zbuf stored bf16.
// ---------------------------------------------------------------------------
__global__ __launch_bounds__(256) void k1_ln_inproj(
    const float* __restrict__ inp, const float* __restrict__ g, const float* __restrict__ b,
    const float* __restrict__ wproj, float* __restrict__ xcin, bf16* __restrict__ zbuf) {
  __shared__ float sx[64][132];   // [pos][k] LN'd input
  __shared__ float sw[128][68];   // [row_local][k_chunk]
  __shared__ float smu[64], srs[64];
  const int tid = threadIdx.x;
  const int rt = blockIdx.x & 3;
  const int pt = blockIdx.x >> 2;
  const int bb = pt >> 6;
  const int pbase = (pt & 63) << 6;

  for (int idx = tid; idx < 64 * CC; idx += 256) {
    int c = idx >> 6, pl = idx & 63;
    sx[pl][c] = inp[((size_t)bb * CC + c) * LL + pbase + pl];
  }
  __syncthreads();
  {
    int pl = tid >> 2, j = tid & 3;
    float s = 0.f, s2 = 0.f;
    for (int c = j; c < CC; c += 4) { float v = sx[pl][c]; s += v; s2 += v * v; }
    s += __shfl_xor(s, 1); s2 += __shfl_xor(s2, 1);
    s += __shfl_xor(s, 2); s2 += __shfl_xor(s2, 2);
    if (j == 0) {
      float mu = s * (1.f / CC);
      smu[pl] = mu;
      srs[pl] = rsqrtf(s2 * (1.f / CC) - mu * mu + 1e-5f);
    }
  }
  __syncthreads();
  for (int idx = tid; idx < 64 * CC; idx += 256) {
    int c = idx & 127, pl = idx >> 7;
    sx[pl][c] = (sx[pl][c] - smu[pl]) * srs[pl] * g[c] + b[c];
  }

  const int pg = tid & 7, rg = tid >> 3;
  float acc[8][4];
#pragma unroll
  for (int j = 0; j < 8; j++)
#pragma unroll
    for (int q = 0; q < 4; q++) acc[j][q] = 0.f;

  for (int kc = 0; kc < CC; kc += 64) {
    __syncthreads();
    for (int idx = tid; idx < 128 * 64; idx += 256) {
      int cl = idx & 63, rl = idx >> 6;
      sw[rl][cl] = wproj[(size_t)(rt * 128 + rl) * CC + kc + cl];
    }
    __syncthreads();
#pragma unroll 4
    for (int i = 0; i < 16; i++) {
      const int k0 = kc + 4 * i, kl0 = 4 * i;
      float4 xv[8], wv[4];
#pragma unroll
      for (int j = 0; j < 8; j++) xv[j] = *(const float4*)&sx[pg + 8 * j][k0];
#pragma unroll
      for (int q = 0; q < 4; q++) wv[q] = *(const float4*)&sw[rg + 32 * q][kl0];
#pragma unroll
      for (int j = 0; j < 8; j++)
#pragma unroll
        for (int q = 0; q < 4; q++) {
          acc[j][q] += xv[j].x * wv[q].x + xv[j].y * wv[q].y
                     + xv[j].z * wv[q].z + xv[j].w * wv[q].w;
        }
    }
  }

#pragma unroll
  for (int j = 0; j < 8; j++) {
    const int p = pbase + pg + 8 * j;
    if (rt < 2) {
      float* dst = xcin + ((size_t)bb * LL + p) * DI + rt * 128;
#pragma unroll
      for (int q = 0; q < 4; q++) dst[rg + 32 * q] = acc[j][q];
    } else {
      bf16* dst = zbuf + ((size_t)bb * LL + p) * DI + (rt - 2) * 128;
#pragma unroll
      for (int q = 0; q < 4; q++) dst[rg + 32 * q] = __float2bfloat16(acc[j][q]);
    }
  }
}

// ---------------------------------------------------------------------------
// K2: depthwise 3x3 conv + bias + silu.
// ---------------------------------------------------------------------------
__global__ __launch_bounds__(256) void k2_dwconv(
    const float* __restrict__ xcin, const float* __restrict__ cw, const float* __restrict__ cb,
    float* __restrict__ xconv) {
  const int w0 = (blockIdx.x & 7) * 8;
  const int hh = (blockIdx.x >> 3) & 63;
  const int bb = blockIdx.x >> 9;
  const int d = threadIdx.x;

  float wv[9];
#pragma unroll
  for (int kk = 0; kk < 9; kk++) wv[kk] = cw[d * 9 + kk];
  const float bias = cb[d];

  float xin[3][10];
#pragma unroll
  for (int kh = 0; kh < 3; kh++) {
    int r = hh + kh - 1;
    bool vr = (r >= 0 && r < HH);
#pragma unroll
    for (int c = 0; c < 10; c++) {
      int cc2 = w0 + c - 1;
      bool vc = (cc2 >= 0 && cc2 < WW);
      xin[kh][c] = (vr && vc) ? xcin[((size_t)bb * LL + r * WW + cc2) * DI + d] : 0.f;
    }
  }
#pragma unroll
  for (int j = 0; j < 8; j++) {
    float acc = bias;
#pragma unroll
    for (int kh = 0; kh < 3; kh++)
#pragma unroll
      for (int kw = 0; kw < 3; kw++)
        acc += wv[kh * 3 + kw] * xin[kh][j + kw];
    xconv[((size_t)bb * LL + hh * WW + w0 + j) * DI + d] = siluf_(acc);
  }
}

// ---------------------------------------------------------------------------
// K3: x_proj GEMM (160x256) -> BCbuf48, LDS-tiled both operands. (R15 form)
// ---------------------------------------------------------------------------
__global__ __launch_bounds__(256) void k3_proj(
    const float* __restrict__ xconv, const float* __restrict__ xpw,
    float* __restrict__ BCbuf) {
  __shared__ float sx[16][68];    // k-chunk of xconv
  __shared__ float sw[160][68];   // k-chunk of x_proj_w
  const int tid = threadIdx.x;
  const int bb = blockIdx.x >> 8;
  const int pbase = (blockIdx.x & 255) << 4;  // 16 positions

  const int pg = tid & 7, rb = tid >> 3;
  float acc[2][5];
#pragma unroll
  for (int j = 0; j < 2; j++)
#pragma unroll
    for (int q = 0; q < 5; q++) acc[j][q] = 0.f;

  for (int kc = 0; kc < DI; kc += 64) {
    __syncthreads();
    for (int idx = tid; idx < 16 * 64; idx += 256) {
      int cl = idx & 63, pl = idx >> 6;
      sx[pl][cl] = xconv[((size_t)bb * LL + pbase + pl) * DI + kc + cl];
    }
    for (int idx = tid; idx < 160 * 64; idx += 256) {
      int cl = idx & 63, rl = idx >> 6;
      sw[rl][cl] = xpw[(size_t)rl * DI + kc + cl];
    }
    __syncthreads();
#pragma unroll 4
    for (int i = 0; i < 16; i++) {
      float4 xv[2], wv[5];
#pragma unroll
      for (int j = 0; j < 2; j++) xv[j] = *(const float4*)&sx[2 * pg + j][4 * i];
#pragma unroll
      for (int q = 0; q < 5; q++) wv[q] = *(const float4*)&sw[rb + 32 * q][4 * i];
#pragma unroll
      for (int j = 0; j < 2; j++)
#pragma unroll
        for (int q = 0; q < 5; q++) {
          acc[j][q] += xv[j].x * wv[q].x + xv[j].y * wv[q].y
                     + xv[j].z * wv[q].z + xv[j].w * wv[q].w;
        }
    }
  }

#pragma unroll
  for (int j = 0; j < 2; j++) {
    const int p = pbase + 2 * pg + j;
#pragma unroll
    for (int q = 0; q < 5; q++) {
      const int r = rb + 32 * q;
      const int k = r / 40, c0 = r - k * 40;
      BCbuf[((size_t)(bb * KK + k) * LL + p) * BCW + c0] = acc[j][q];
    }
  }
}

// ---------------------------------------------------------------------------
// K4a: chunked scan phase 1 with inline dt. Stores sumdt (fp32) + Bc (bf16).
// ---------------------------------------------------------------------------
__global__ __launch_bounds__(256) void k4a_chunk(
    const float* __restrict__ xconv, const float* __restrict__ BCbuf,
    const float* __restrict__ A_logs, const float* __restrict__ dtw,
    const float* __restrict__ dtb,
    float* __restrict__ csS, bf16* __restrict__ csB) {
  __shared__ float sBC[CL][26];
  const int d = threadIdx.x;
  const int chunk = blockIdx.x & (NC - 1);
  const int t = blockIdx.x / NC;
  const int k = t & 3;
  const int bb = t >> 2;
  const int bk = bb * KK + k;
  const int base = chunk * CL;

  for (int idx = d; idx < CL * 24; idx += 256) {
    int ii = idx / 24, j = idx - ii * 24;
    int pos = scan_pos(k, base + ii);
    sBC[ii][j] = BCbuf[((size_t)bk * LL + pos) * BCW + j];
  }
  float a[NS];
  bool fast = true;
#pragma unroll
  for (int n = 0; n < NS; n++) {
    a[n] = -__expf(A_logs[((size_t)k * DI + d) * NS + n]);
    fast = fast && (fabsf(a[n] + (float)(n + 1)) < 1e-3f * (n + 1));
  }
  const float* wdt = dtw + ((size_t)k * DI + d) * 8;
  const float4 wd0 = *(const float4*)wdt;
  const float4 wd1 = *(const float4*)(wdt + 4);
  const float bdt = dtb[k * DI + d];
  __syncthreads();

  const float* x_p = xconv + (size_t)bb * LL * DI + d;

  float Bc[NS];
#pragma unroll
  for (int n = 0; n < NS; n++) Bc[n] = 0.f;
  float sumdt = 0.f;

  if (fast) {
#pragma unroll
    for (int half = 0; half < CL / 8; half++) {
      float xvr[8];
#pragma unroll
      for (int j = 0; j < 8; j++)
        xvr[j] = x_p[(size_t)scan_pos(k, base + half * 8 + j) * DI];
#pragma unroll
      for (int j = 0; j < 8; j++) {
        const int ii = half * 8 + j;
        const float* dr = sBC[ii];
        float u = bdt + wd0.x * dr[0] + wd0.y * dr[1] + wd0.z * dr[2] + wd0.w * dr[3]
                      + wd1.x * dr[4] + wd1.y * dr[5] + wd1.z * dr[6] + wd1.w * dr[7];
        float t2 = __expf(u);
        float E = __builtin_amdgcn_rcpf(1.f + t2);   // = exp(-dt)
        float dt = u > 20.f ? u : -0.69314718056f * __log2f(E);
        sumdt += dt;
        float dtx = dt * xvr[j];
        float E2 = E * E;
        float dA1 = E, dA2 = E2;
#pragma unroll
        for (int n = 0; n < NS; n += 2) {
          Bc[n] = dA1 * Bc[n] + dtx * sBC[ii][8 + n];
          Bc[n + 1] = dA2 * Bc[n + 1] + dtx * sBC[ii][9 + n];
          dA1 *= E2; dA2 *= E2;
        }
      }
    }
  } else {
#pragma unroll 2
    for (int ii = 0; ii < CL; ii++) {
      int pos = scan_pos(k, base + ii);
      float xv = x_p[(size_t)pos * DI];
      const float* dr = sBC[ii];
      float u = bdt + wd0.x * dr[0] + wd0.y * dr[1] + wd0.z * dr[2] + wd0.w * dr[3]
                    + wd1.x * dr[4] + wd1.y * dr[5] + wd1.z * dr[6] + wd1.w * dr[7];
      float t2 = __expf(u);
      float dt = u > 20.f ? u : log1pf(t2);
      sumdt += dt;
      float dtx = dt * xv;
#pragma unroll
      for (int n = 0; n < NS; n++) {
        float dA = __expf(dt * a[n]);
        Bc[n] = dA * Bc[n] + dtx * sBC[ii][8 + n];
      }
    }
  }
  csS[((size_t)bk * NC + chunk) * DI + d] = sumdt;
  size_t e = ((size_t)(bk * NC + chunk) * NS) * DI + d;
#pragma unroll
  for (int n = 0; n < NS; n++)
    csB[e + (size_t)n * DI] = __float2bfloat16(Bc[n]);
}

// ---------------------------------------------------------------------------
// K4b: scan NC chunk summaries -> h_in (bf16). Ap[n] = exp(a_n * sumdt).
// d-split x2: grid = BB*KK*NS*2 = 256 blocks x 128 threads (all CUs busy).
// ---------------------------------------------------------------------------
__global__ __launch_bounds__(128) void k4b_scanchunks(
    const float* __restrict__ csS, const bf16* __restrict__ csB,
    const float* __restrict__ A_logs, bf16* __restrict__ hin) {
  const int d = threadIdx.x + ((blockIdx.x & 1) << 7);
  const int n = (blockIdx.x >> 1) & (NS - 1);
  const int bk = blockIdx.x >> 5;
  const int k = bk & 3;
  const float an = -__expf(A_logs[((size_t)k * DI + d) * NS + n]);
  const size_t strideB = (size_t)NS * DI;
  size_t e = ((size_t)bk * NC * NS + n) * DI + d;
  float H = 0.f;
  for (int c0 = 0; c0 < NC; c0 += 16) {
    float Ea[16], Bv[16];
#pragma unroll
    for (int j = 0; j < 16; j++) {
      Ea[j] = an * csS[((size_t)bk * NC + c0 + j) * DI + d];
      Bv[j] = __bfloat162float(csB[e + (size_t)j * strideB]);
    }
#pragma unroll
    for (int j = 0; j < 16; j++) Ea[j] = __expf(Ea[j]);
#pragma unroll
    for (int j = 0; j < 16; j++) {
      hin[e + (size_t)j * strideB] = __float2bfloat16(H);
      H = Ea[j] * H + Bv[j];
    }
    e += (size_t)16 * strideB;
  }
}

// ---------------------------------------------------------------------------
// K4c: chunked scan phase 3 — recurrence from h_in (bf16), emit y (bf16).
// ---------------------------------------------------------------------------
__global__ __launch_bounds__(256) void k4c_scan(
    const float* __restrict__ xconv, const float* __restrict__ BCbuf,
    const float* __restrict__ A_logs, const float* __restrict__ dtw,
    const float* __restrict__ dtb, const float* __restrict__ Ds,
    const bf16* __restrict__ hin, bf16* __restrict__ ys) {
  __shared__ float sBC[CL][BCW];
  const int d = threadIdx.x;
  const int chunk = blockIdx.x & (NC - 1);
  const int t = blockIdx.x / NC;
  const int k = t & 3;
  const int bb = t >> 2;
  const int bk = bb * KK + k;
  const int base = chunk * CL;

  for (int idx = d; idx < CL * 40; idx += 256) {
    int ii = idx / 40, j = idx - ii * 40;
    int pos = scan_pos(k, base + ii);
    sBC[ii][j] = BCbuf[((size_t)bk * LL + pos) * BCW + j];
  }
  float a[NS], h[NS];
  bool fast = true;
  const size_t eh = ((size_t)(bk * NC + chunk) * NS) * DI + d;
#pragma unroll
  for (int n = 0; n < NS; n++) {
    a[n] = -__expf(A_logs[((size_t)k * DI + d) * NS + n]);
    fast = fast && (fabsf(a[n] + (float)(n + 1)) < 1e-3f * (n + 1));
    h[n] = __bfloat162float(hin[eh + (size_t)n * DI]);
  }
  const float* wdt = dtw + ((size_t)k * DI + d) * 8;
  const float4 wd0 = *(const float4*)wdt;
  const float4 wd1 = *(const float4*)(wdt + 4);
  const float bdt = dtb[k * DI + d];
  const float Dd = Ds[k * DI + d];
  __syncthreads();

  const float* x_p = xconv + (size_t)bb * LL * DI + d;
  bf16* ys_p = ys + (size_t)bk * LL * DI + d;

  if (fast) {
#pragma unroll
    for (int half = 0; half < CL / 8; half++) {
      float xvr[8];
#pragma unroll
      for (int j = 0; j < 8; j++)
        xvr[j] = x_p[(size_t)scan_pos(k, base + half * 8 + j) * DI];
#pragma unroll
      for (int j = 0; j < 8; j++) {
        const int ii = half * 8 + j;
        const float* dr = sBC[ii];
        float u = bdt + wd0.x * dr[0] + wd0.y * dr[1] + wd0.z * dr[2] + wd0.w * dr[3]
                      + wd1.x * dr[4] + wd1.y * dr[5] + wd1.z * dr[6] + wd1.w * dr[7];
        float t2 = __expf(u);
        float E = __builtin_amdgcn_rcpf(1.f + t2);   // = exp(-dt)
        float dt = u > 20.f ? u : -0.69314718056f * __log2f(E);
        float dtx = dt * xvr[j];
        float y = xvr[j] * Dd;
        float E2 = E * E;
        float dA1 = E, dA2 = E2;
#pragma unroll
        for (int n = 0; n < NS; n += 2) {
          h[n] = dA1 * h[n] + dtx * sBC[ii][8 + n];
          y += h[n] * sBC[ii][24 + n];
          h[n + 1] = dA2 * h[n + 1] + dtx * sBC[ii][9 + n];
          y += h[n + 1] * sBC[ii][25 + n];
          dA1 *= E2; dA2 *= E2;
        }
        ys_p[(size_t)scan_pos(k, base + ii) * DI] = __float2bfloat16(y);
      }
    }
  } else {
#pragma unroll 2
    for (int ii = 0; ii < CL; ii++) {
      int pos = scan_pos(k, base + ii);
      float xv = x_p[(size_t)pos * DI];
      const float* dr = sBC[ii];
      float u = bdt + wd0.x * dr[0] + wd0.y * dr[1] + wd0.z * dr[2] + wd0.w * dr[3]
                    + wd1.x * dr[4] + wd1.y * dr[5] + wd1.z * dr[6] + wd1.w * dr[7];
      float t2 = __expf(u);
      float dt = u > 20.f ? u : log1pf(t2);
      float dtx = dt * xv;
      float y = xv * Dd;
#pragma unroll
      for (int n = 0; n < NS; n++) {
        float dA = __expf(dt * a[n]);
        h[n] = dA * h[n] + dtx * sBC[ii][8 + n];
        y += h[n] * sBC[ii][24 + n];
      }
      ys_p[(size_t)pos * DI] = __float2bfloat16(y);
    }
  }
}

// ---------------------------------------------------------------------------
// K5: FUSED. 4-dir sum (bf16 ys) + out_norm LN + silu(bf16 z) into LDS, then
// out_proj GEMM + skip -> xresT (NCHW); LN2 -> ln2. (R26 proven: k-chunk 64)
// ---------------------------------------------------------------------------
__global__ __launch_bounds__(256) void k5_fused(
    const bf16* __restrict__ ys, const bf16* __restrict__ zbuf,
    const float* __restrict__ ong, const float* __restrict__ onb,
    const float* __restrict__ opw,
    const float* __restrict__ inp, const float* __restrict__ sk,
    const float* __restrict__ g2, const float* __restrict__ b2,
    float* __restrict__ xresT, float* __restrict__ ln2) {
  __shared__ float sy[16][260];   // activated input (full K)
  __shared__ float sw[128][68];   // k-chunk of opw
  __shared__ float sr[16][132];
  __shared__ float smu[16], srs[16];
  const int tid = threadIdx.x;
  const int bb = blockIdx.x >> 8;
  const int pbase = (blockIdx.x & 255) << 4;  // 16 positions

  for (int idx = tid; idx < 16 * DI; idx += 256) {
    int d = idx & 255, pl = idx >> 8;
    size_t o0 = (((size_t)bb * KK + 0) * LL + pbase + pl) * DI + d;
    const size_t st = (size_t)LL * DI;
    sy[pl][d] = __bfloat162float(ys[o0]) + __bfloat162float(ys[o0 + st])
              + __bfloat162float(ys[o0 + 2 * st]) + __bfloat162float(ys[o0 + 3 * st]);
  }
  __syncthreads();
  {
    int pl = tid >> 4, j = tid & 15;
    float s = 0.f, s2 = 0.f;
    for (int d = j; d < DI; d += 16) { float v = sy[pl][d]; s += v; s2 += v * v; }
#pragma unroll
    for (int m = 1; m < 16; m <<= 1) { s += __shfl_xor(s, m); s2 += __shfl_xor(s2, m); }
    if (j == 0) {
      float mu = s * (1.f / DI);
      smu[pl] = mu;
      srs[pl] = rsqrtf(s2 * (1.f / DI) - mu * mu + 1e-5f);
    }
  }
  __syncthreads();
  for (int idx = tid; idx < 16 * DI; idx += 256) {
    int d = idx & 255, pl = idx >> 8;
    float zv = __bfloat162float(zbuf[((size_t)bb * LL + pbase + pl) * DI + d]);
    sy[pl][d] = ((sy[pl][d] - smu[pl]) * srs[pl] * ong[d] + onb[d]) * siluf_(zv);
  }

  const int pg = tid & 7, rb = tid >> 3;      // pos-pair group, c-base
  float acc[2][4];
#pragma unroll
  for (int j = 0; j < 2; j++)
#pragma unroll
    for (int q = 0; q < 4; q++) acc[j][q] = 0.f;

  for (int kc = 0; kc < DI; kc += 64) {
    __syncthreads();
    for (int idx = tid; idx < 128 * 64; idx += 256) {
      int cl = idx & 63, rl = idx >> 6;
      sw[rl][cl] = opw[(size_t)rl * DI + kc + cl];
    }
    __syncthreads();
#pragma unroll 4
    for (int i = 0; i < 16; i++) {
      float4 xv[2], wv[4];
#pragma unroll
      for (int j = 0; j < 2; j++) xv[j] = *(const float4*)&sy[2 * pg + j][kc + 4 * i];
#pragma unroll
      for (int q = 0; q < 4; q++) wv[q] = *(const float4*)&sw[rb + 32 * q][4 * i];
#pragma unroll
      for (int j = 0; j < 2; j++)
#pragma unroll
        for (int q = 0; q < 4; q++) {
          acc[j][q] += xv[j].x * wv[q].x + xv[j].y * wv[q].y
                     + xv[j].z * wv[q].z + xv[j].w * wv[q].w;
        }
    }
  }

#pragma unroll
  for (int j = 0; j < 2; j++) {
    const int p = pbase + 2 * pg + j;
#pragma unroll
    for (int q = 0; q < 4; q++) {
      const int c = rb + 32 * q;
      float r = inp[((size_t)bb * CC + c) * LL + p] * sk[c] + acc[j][q];
      sr[2 * pg + j][c] = r;
    }
  }
  __syncthreads();
  {
    int pl = tid >> 4, jj = tid & 15;
    float s = 0.f, s2 = 0.f;
    for (int c = jj; c < CC; c += 16) { float v = sr[pl][c]; s += v; s2 += v * v; }
#pragma unroll
    for (int m = 1; m < 16; m <<= 1) { s += __shfl_xor(s, m); s2 += __shfl_xor(s2, m); }
    if (jj == 0) {
      float mu = s * (1.f / CC);
      smu[pl] = mu;
      srs[pl] = rsqrtf(s2 * (1.f / CC) - mu * mu + 1e-5f);
    }
  }
  __syncthreads();
  for (int idx = tid; idx < 16 * CC; idx += 256) {
    int pl = idx & 15, c = idx >> 4;
    float r = sr[pl][c];
    size_t o = ((size_t)bb * CC + c) * LL + pbase + pl;
    xresT[o] = r;
    ln2[o] = (r - smu[pl]) * srs[pl] * g2[c] + b2[c];
  }
}

// ---------------------------------------------------------------------------
// K6a: CAB conv1 partials. K-split over input channels (8 chunks of 16).
// ---------------------------------------------------------------------------
__global__ __launch_bounds__(256) void k6a_conv1(
    const float* __restrict__ ln2, const float* __restrict__ w1,
    float* __restrict__ pc1) {
  __shared__ float sIn[16][6][68];
  __shared__ float sw[16 * 9 * OC1];
  const int tid = threadIdx.x;
  const int icq = blockIdx.x & 7;
  const int h4  = (blockIdx.x >> 3) & 15;
  const int bb  = blockIdx.x >> 7;
  const int icb = icq * 16;

  for (int idx = tid; idx < 16 * 6 * 66; idx += 256) {
    int i = idx / 396, rem = idx % 396;
    int rr = rem / 66, j = rem % 66;
    int r = h4 * 4 + rr - 1, c2 = j - 1;
    float v = 0.f;
    if (r >= 0 && r < HH && c2 >= 0 && c2 < WW)
      v = ln2[((size_t)bb * CC + icb + i) * LL + r * WW + c2];
    sIn[i][rr][j] = v;
  }
  for (int idx = tid; idx < OC1 * 16 * 9; idx += 256) {
    int oc = idx / 144, rem = idx % 144;
    int i = rem / 9, kk = rem % 9;
    sw[(i * 9 + kk) * OC1 + oc] = w1[((size_t)oc * CC + icb + i) * 9 + kk];
  }
  __syncthreads();

  const int wq = tid & 7, hq = (tid >> 3) & 3, ocg = tid >> 5;
  float acc[6][8];
#pragma unroll
  for (int q = 0; q < 6; q++)
#pragma unroll
    for (int ww = 0; ww < 8; ww++) acc[q][ww] = 0.f;

  for (int i = 0; i < 16; i++) {
    float xin[3][10];
#pragma unroll
    for (int kh = 0; kh < 3; kh++)
#pragma unroll
      for (int j = 0; j < 10; j++) xin[kh][j] = sIn[i][hq + kh][wq * 8 + j];
#pragma unroll
    for (int q = 0; q < 6; q++) {
      int oc = ocg + 8 * q;
      if (oc >= OC1) break;
      float wv[9];
#pragma unroll
      for (int kk = 0; kk < 9; kk++) wv[kk] = sw[(i * 9 + kk) * OC1 + oc];
#pragma unroll
      for (int kh = 0; kh < 3; kh++)
#pragma unroll
        for (int kw = 0; kw < 3; kw++)
#pragma unroll
          for (int ww = 0; ww < 8; ww++)
            acc[q][ww] += wv[kh * 3 + kw] * xin[kh][ww + kw];
    }
  }

  const int hrow = h4 * 4 + hq;
#pragma unroll
  for (int q = 0; q < 6; q++) {
    int oc = ocg + 8 * q;
    if (oc >= OC1) break;
    float* dst = pc1 + (((size_t)icq * BB + bb) * OC1 + oc) * LL + hrow * WW + wq * 8;
    *(float4*)dst       = make_float4(acc[q][0], acc[q][1], acc[q][2], acc[q][3]);
    *(float4*)(dst + 4) = make_float4(acc[q][4], acc[q][5], acc[q][6], acc[q][7]);
  }
}

// ---------------------------------------------------------------------------
// K6b: reduce 8 partials + bias + exact GELU -> t1. L-split x4:
// grid = BB*42*4 = 336 blocks, exactly 1 float4-iteration per thread.
// ---------------------------------------------------------------------------
__global__ __launch_bounds__(256) void k6b_reduce(
    const float* __restrict__ pc1, const float* __restrict__ b1,
    float* __restrict__ t1) {
  const int seg = blockIdx.x & 3;
  const int t = blockIdx.x >> 2;
  const int oc = t % OC1;
  const int bb = t / OC1;
  const float bias = b1[oc];
  const size_t st = (size_t)BB * OC1 * LL;
  const float* src = pc1 + ((size_t)bb * OC1 + oc) * LL;
  float* dst = t1 + ((size_t)bb * OC1 + oc) * LL;
  const int i0 = seg * (LL / 16), i1 = i0 + LL / 16;   // float4 index range
  for (int i = i0 + (int)threadIdx.x; i < i1; i += 256) {
    float4 s = ((const float4*)src)[i];
#pragma unroll
    for (int icq = 1; icq < 8; icq++) {
      float4 v = *(const float4*)(src + (size_t)icq * st + i * 4);
      s.x += v.x; s.y += v.y; s.z += v.z; s.w += v.w;
    }
    float r[4] = {s.x + bias, s.y + bias, s.z + bias, s.w + bias};
#pragma unroll
    for (int q = 0; q < 4; q++)
      r[q] = 0.5f * r[q] * (1.f + erff(r[q] * 0.70710678118654752f));
    ((float4*)dst)[i] = make_float4(r[0], r[1], r[2], r[3]);
  }
}

// ---------------------------------------------------------------------------
// K7: CAB conv2 partials. ic K-split x2 (chunks of 21); transposed weight
// tile swT[32][196] (conflict-free staging + reads). (R17 proven form)
// ---------------------------------------------------------------------------
__global__ __launch_bounds__(256) void k7_conv2(
    const float* __restrict__ t1, const float* __restrict__ w2,
    float* __restrict__ pc2) {
  __shared__ float sIn[21][4][68];
  __shared__ float swT[32 * 196];   // [oc_local][i*9+kk], row pad 196
  const int tid = threadIdx.x;
  const int icq = blockIdx.x & 1;
  const int h2  = (blockIdx.x >> 1) & 31;
  const int ocq = (blockIdx.x >> 6) & 3;
  const int bb  = blockIdx.x >> 8;
  const int icb = icq * 21;

  for (int idx = tid; idx < 21 * 4 * 66; idx += 256) {
    int i = idx / 264, rem = idx % 264;
    int rr = rem / 66, j = rem % 66;
    int r = h2 * 2 + rr - 1, c2 = j - 1;
    float v = 0.f;
    if (r >= 0 && r < HH && c2 >= 0 && c2 < WW)
      v = t1[((size_t)bb * OC1 + icb + i) * LL + r * WW + c2];
    sIn[i][rr][j] = v;
  }
  for (int idx = tid; idx < 32 * 189; idx += 256) {
    int ol = idx / 189, ikk = idx % 189;
    swT[ol * 196 + ikk] = w2[(size_t)(ocq * 32 + ol) * (OC1 * 9) + icb * 9 + ikk];
  }
  __syncthreads();

  const int wq = tid & 7, hq = (tid >> 3) & 1, ocg = tid >> 4;
  float acc[2][8];
#pragma unroll
  for (int q = 0; q < 2; q++)
#pragma unroll
    for (int ww = 0; ww < 8; ww++) acc[q][ww] = 0.f;

  for (int i = 0; i < 21; i++) {
    float xin[3][10];
#pragma unroll
    for (int kh = 0; kh < 3; kh++)
#pragma unroll
      for (int j = 0; j < 10; j++) xin[kh][j] = sIn[i][hq + kh][wq * 8 + j];
#pragma unroll
    for (int q = 0; q < 2; q++) {
      int ol = ocg + 16 * q;
      float wv[9];
#pragma unroll
      for (int kk = 0; kk < 9; kk++) wv[kk] = swT[ol * 196 + i * 9 + kk];
#pragma unroll
      for (int kh = 0; kh < 3; kh++)
#pragma unroll
        for (int kw = 0; kw < 3; kw++)
#pragma unroll
          for (int ww = 0; ww < 8; ww++)
            acc[q][ww] += wv[kh * 3 + kw] * xin[kh][ww + kw];
    }
  }

  const int hrow = h2 * 2 + hq;
#pragma unroll
  for (int q = 0; q < 2; q++) {
    int oc = ocq * 32 + ocg + 16 * q;
    float* dst = pc2 + (((size_t)icq * BB + bb) * CC + oc) * LL + hrow * WW + wq * 8;
    *(float4*)dst       = make_float4(acc[q][0], acc[q][1], acc[q][2], acc[q][3]);
    *(float4*)(dst + 4) = make_float4(acc[q][4], acc[q][5], acc[q][6], acc[q][7]);
  }
}

// ---------------------------------------------------------------------------
// K8: reduce 2 conv2 partials + bias -> t2; partial sums of mean. L-split x2:
// grid = BB*CC*2 = 512 blocks; smean_p[half][bc] holds half-mean (pre-scaled).
// ---------------------------------------------------------------------------
__global__ __launch_bounds__(256) void k8_mean(
    const float* __restrict__ pc2, const float* __restrict__ b2,
    float* __restrict__ t2, float* __restrict__ smean_p) {
  __shared__ float red[4];
  const int half = blockIdx.x & 1;
  const int bc = blockIdx.x >> 1;
  const int bb = bc >> 7, c = bc & 127;
  const float bias = b2[c];
  const size_t st = (size_t)BB * CC * LL;
  const float* src = pc2 + ((size_t)bb * CC + c) * LL;
  float* dst = t2 + (size_t)bc * LL;
  float s = 0.f;
  const int i0 = half * (LL / 8), i1 = i0 + LL / 8;    // float4 index range
  for (int i = i0 + (int)threadIdx.x; i < i1; i += 256) {
    float4 v0 = ((const float4*)src)[i];
    float4 v1 = *(const float4*)(src + st + i * 4);
    float4 r = make_float4(v0.x + v1.x + bias, v0.y + v1.y + bias,
                           v0.z + v1.z + bias, v0.w + v1.w + bias);
    ((float4*)dst)[i] = r;
    s += r.x + r.y + r.z + r.w;
  }
#pragma unroll
  for (int m = 1; m < 64; m <<= 1) s += __shfl_xor(s, m);
  if ((threadIdx.x & 63) == 0) red[threadIdx.x >> 6] = s;
  __syncthreads();
  if (threadIdx.x == 0)
    smean_p[half * (BB * CC) + bc] = (red[0] + red[1] + red[2] + red[3]) * (1.f / LL);
}

// ---------------------------------------------------------------------------
// K10: CA MLP (recomputed per block from 2 smean partials) + final combine.
// L-split x2: grid = BB*CC*2 = 512 blocks.
// ---------------------------------------------------------------------------
__global__ __launch_bounds__(256) void k10_final(
    const float* __restrict__ xresT, const float* __restrict__ t2,
    const float* __restrict__ smean_p,
    const float* __restrict__ cw1, const float* __restrict__ cb1,
    const float* __restrict__ cw2, const float* __restrict__ cb2,
    const float* __restrict__ sk2, float* __restrict__ out) {
  __shared__ float mid[4];
  const int tid = threadIdx.x;
  const int phalf = blockIdx.x & 1;
  const int bc = blockIdx.x >> 1;
  const int bb = bc >> 7, c = bc & 127;

  {
    const int wv = tid >> 6, ln = tid & 63;
    const float* sp0 = smean_p;
    const float* sp1 = smean_p + BB * CC;
    float m0 = sp0[bb * CC + ln] + sp1[bb * CC + ln];
    float m1 = sp0[bb * CC + 64 + ln] + sp1[bb * CC + 64 + ln];
    float s = cw1[wv * CC + ln] * m0 + cw1[wv * CC + 64 + ln] * m1;
#pragma unroll
    for (int m = 1; m < 64; m <<= 1) s += __shfl_xor(s, m);
    if (ln == 0) mid[wv] = fmaxf(s + cb1[wv], 0.f);
  }
  __syncthreads();
  float a = cb2[c];
#pragma unroll
  for (int m = 0; m < 4; m++) a += cw2[c * 4 + m] * mid[m];
  const float sv = sigmoidf_(a);

  const float ss = sk2[c];
  const float* t2r = t2 + (size_t)bc * LL;
  const float* xrt = xresT + (size_t)bc * LL;
  float* outr = out + (size_t)bc * LL;
  const int e0 = phalf * (LL / 2), e1 = e0 + LL / 2;
  for (int i = e0 + tid; i < e1; i += 256)
    outr[i] = xrt[i] * ss + t2r[i] * sv;
}

// ---------------------------------------------------------------------------

extern "C" void kernel_launch(void* const* d_in, const int* in_sizes, int n_in,
                              void* d_out, int out_size, void* d_ws, size_t ws_size,
                              hipStream_t stream) {
  const float* input      = (const float*)d_in[0];
  const float* ln1_g      = (const float*)d_in[1];
  const float* ln1_b      = (const float*)d_in[2];
  const float* skip_scale = (const float*)d_in[3];
  const float* skip_scale2= (const float*)d_in[4];
  const float* ln2_g      = (const float*)d_in[5];
  const float* ln2_b      = (const float*)d_in[6];
  const float* in_proj_w  = (const float*)d_in[7];
  const float* conv_w     = (const float*)d_in[8];
  const float* conv_b     = (const float*)d_in[9];
  const float* x_proj_w   = (const float*)d_in[10];
  const float* dt_w       = (const float*)d_in[11];
  const float* dt_b       = (const float*)d_in[12];
  const float* A_logs     = (const float*)d_in[13];
  const float* Ds         = (const float*)d_in[14];
  const float* out_norm_g = (const float*)d_in[15];
  const float* out_norm_b = (const float*)d_in[16];
  const float* out_proj_w = (const float*)d_in[17];
  const float* cab_w1     = (const float*)d_in[18];
  const float* cab_b1     = (const float*)d_in[19];
  const float* cab_w2     = (const float*)d_in[20];
  const float* cab_b2     = (const float*)d_in[21];
  const float* ca_w1      = (const float*)d_in[22];
  const float* ca_b1      = (const float*)d_in[23];
  const float* ca_w2      = (const float*)d_in[24];
  const float* ca_b2      = (const float*)d_in[25];

  float* ws = (float*)d_ws;
  float* xcin  = ws;                                   // B*L*256 f32
  float* zb_f  = xcin + (size_t)BB * LL * DI;          // B*L*256 region (bf16 used)
  bf16*  zbuf  = (bf16*)zb_f;
  float* xconv = zb_f + (size_t)BB * LL * DI;          // B*L*256 f32
  float* BCbuf = xconv + (size_t)BB * LL * DI;         // B*4*L*48 f32
  float* ysb_f = BCbuf + (size_t)BB * KK * LL * BCW;   // B*4*L*256 region
  float* xresT = ysb_f + (size_t)BB * KK * LL * DI;    // B*128*L (NCHW) f32
  float* ln2b  = xresT + (size_t)BB * LL * CC;         // B*128*L f32
  float* t1b   = ln2b + (size_t)BB * CC * LL;          // B*42*L f32
  float* t2b   = t1b + (size_t)BB * OC1 * LL;          // B*128*L f32
  float* smean = t2b + (size_t)BB * CC * LL;           // 2 x B*128 (partials)
  float* hin_f = smean + 2 * BB * CC;                  // B*K*NC*NS*DI region (bf16)
  bf16*  hinbuf= (bf16*)hin_f;
  float* csS   = hin_f + (size_t)BB * KK * NC * NS * DI;  // B*K*NC*DI f32 (sumdt)
  // csB (bf16) aliases ysb region start; ys (bf16) same region (disjoint
  // lifetimes: csB k4a->k4b, ys k4c->k5). pc1/pc2 (f32) alias ysb after k5.
  bf16*  csB   = (bf16*)ysb_f;
  bf16*  ysbuf = (bf16*)ysb_f;
  float* pc1   = ysb_f;
  float* pc2   = ysb_f + (size_t)3 * 1024 * 1024;

  k1_ln_inproj<<<512, 256, 0, stream>>>(input, ln1_g, ln1_b, in_proj_w, xcin, zbuf);
  k2_dwconv<<<BB * HH * (WW / 8), 256, 0, stream>>>(xcin, conv_w, conv_b, xconv);
  k3_proj<<<BB * (LL / K3_POS), 256, 0, stream>>>(xconv, x_proj_w, BCbuf);
  k4a_chunk<<<BB * KK * NC, 256, 0, stream>>>(xconv, BCbuf, A_logs, dt_w, dt_b, csS, csB);
  k4b_scanchunks<<<BB * KK * NS * 2, 128, 0, stream>>>(csS, csB, A_logs, hinbuf);
  k4c_scan<<<BB * KK * NC, 256, 0, stream>>>(xconv, BCbuf, A_logs, dt_w, dt_b, Ds, hinbuf, ysbuf);
  k5_fused<<<BB * (LL / 16), 256, 0, stream>>>(ysbuf, zbuf, out_norm_g, out_norm_b, out_proj_w,
                                               input, skip_scale, ln2_g, ln2_b, xresT, ln2b);
  k6a_conv1<<<BB * 16 * 8, 256, 0, stream>>>(ln2b, cab_w1, pc1);
  k6b_reduce<<<BB * OC1 * 4, 256, 0, stream>>>(pc1, cab_b1, t1b);
  k7_conv2<<<BB * 4 * 32 * 2, 256, 0, stream>>>(t1b, cab_w2, pc2);
  k8_mean<<<BB * CC * 2, 256, 0, stream>>>(pc2, cab_b2, t2b, smean);
  k10_final<<<BB * CC * 2, 256, 0, stream>>>(xresT, t2b, smean, ca_w1, ca_b1, ca_w2, ca_b2,
                                             skip_scale2, (float*)d_out);
}